// Round 6
// baseline (111.216 us; speedup 1.0000x reference)
//
#include <hip/hip_runtime.h>

#define B 64
#define N 1024
#define E 16384
#define WPR 32          // words per adjacency row = N/32
#define NITER 5
#define CSR_SLOTS (E + N)   // even-aligned per-node alloc: <=1 pad slot/node
#define MAXP 20             // pair-words cached in registers (deg<=40; global fallback beyond)
#define SENT_PAIR 0x04000400u   // (N<<16)|N : both halves index s_lab[N]==0
#define CSR_STRIDE 32       // u32 per node in global CSR (64 u16 slots)

// ---- workspace layout (bytes) ---- (NO memset: everything we read is
// fully stored first; harness 0xAA poison harmless)
#define FEATS_OFF 0
#define DIAG_OFF  ((size_t)B * N * 4)
#define CSR_OFF   ((size_t)1 << 20)                          // 1MB
#define DEG_OFF   (CSR_OFF + (size_t)B * N * CSR_STRIDE * 4) // +8MB
#define KPART_OFF (DEG_OFF + (size_t)B * N * 4)              // +256KB
#define OVFP_OFF  (KPART_OFF + 4096)

// R28: Phase A (bitmask dedupe + CSR build) moved OUT of the graph-
// synchronous mega-kernel into csr_k: 256 blocks (4/graph, 256 rows each,
// 32KB LDS bitmask) -> fixed-stride global CSR (no start-scan) + deg array
// + K partials, using 4x more CUs. wl_mega's Phase A collapses to ~20
// global CSR loads/thread (5 fewer barriers, no 128KB zero / scatter /
// readback / pack). deg>62 rows set a per-graph overflow flag -> that graph
// takes the old in-kernel Phase A (kept; block-uniform branch). Phase B =
// R25's best-measured structure (R26/R27 variants were neutral/worse).
__global__ void __launch_bounds__(1024) csr_k(const int* __restrict__ src,
                                              const int* __restrict__ dstp,
                                              unsigned int* __restrict__ csr,
                                              unsigned int* __restrict__ degarr,
                                              unsigned int* __restrict__ kpart,
                                              unsigned int* __restrict__ ovfp) {
    __shared__ unsigned int bm[256 * WPR];          // 32KB bitmask (swizzled)
    __shared__ int s_kp[16];
    __shared__ int s_ovf;
    int blk = blockIdx.x, t = threadIdx.x;
    int lane = t & 63, w = t >> 6;
    int b = blk >> 2, q = blk & 3, base = q << 8;   // rows [base, base+256)

#pragma unroll
    for (int k = 0; k < 2; ++k)                     // zero 32KB
        ((uint4*)bm)[t + k * 1024] = make_uint4(0, 0, 0, 0);
    if (t == 0) s_ovf = 0;
    __syncthreads();

    const int* sg = src + (size_t)b * E;
    const int* dgp = dstp + (size_t)b * E;
#pragma unroll
    for (int k = 0; k < 16; ++k) {                  // scan ALL graph edges, keep own rows
        int es = sg[t + k * 1024];
        int ed = dgp[t + k * 1024];
        int rr = es - base;
        if ((unsigned)rr < 256u) {
            int wlog = ed >> 5;                     // logical word 0..31
            int g = wlog >> 2;                      // logical group 0..7
            int p = (g + rr) & 7;                   // swizzled slot
            atomicOr(&bm[rr * WPR + p * 4 + (wlog & 3)], 1u << (ed & 31));
        }
    }
    __syncthreads();

    // 4 threads per row: each owns 2 logical groups (8 words)
    int r = t >> 2, sub = t & 3;
    const uint4* row4 = (const uint4*)(bm + r * WPR);
    uint4 ra = row4[(sub * 2 + r) & 7];             // logical group sub*2
    uint4 rb = row4[(sub * 2 + 1 + r) & 7];         // logical group sub*2+1
    int pdeg = __popc(ra.x) + __popc(ra.y) + __popc(ra.z) + __popc(ra.w)
             + __popc(rb.x) + __popc(rb.y) + __popc(rb.z) + __popc(rb.w);
    int d01 = pdeg + __shfl_xor(pdeg, 1);
    int deg = d01 + __shfl_xor(d01, 2);             // full row degree (all 4 subs)
    int pre = 0;                                    // exclusive prefix within quad
    {
        int v1 = __shfl_up(pdeg, 1); if ((lane & 3) >= 1) pre += v1;
        int v2 = __shfl_up(pdeg, 2); if ((lane & 3) >= 2) pre += v2;
        int v3 = __shfl_up(pdeg, 3); if ((lane & 3) >= 3) pre += v3;
    }
    int node = b * N + base + r;
    if (sub == 0) degarr[node] = (unsigned)deg;
    if (deg <= 62) {                                // fixed-stride pack (sorted)
        unsigned short* row16 = (unsigned short*)(csr + (size_t)node * CSR_STRIDE);
        int idx = pre;
        unsigned int wv[8] = { ra.x, ra.y, ra.z, ra.w, rb.x, rb.y, rb.z, rb.w };
#pragma unroll
        for (int c = 0; c < 8; ++c) {
            unsigned int word = wv[c];
            int gg = sub * 2 + (c >> 2);            // logical group
            int bb = (gg * 4 + (c & 3)) << 5;       // column base
            while (word) {
                int j = __ffs(word) - 1;
                word &= word - 1;
                row16[idx++] = (unsigned short)(bb + j);
            }
        }
        if (sub == 0) {                             // parity sentinels (slots<64)
            row16[deg] = (unsigned short)N;
            row16[deg + 1] = (unsigned short)N;
        }
    } else {
        s_ovf = 1;                                  // graph falls back in wl_mega
    }
    int km = deg;                                   // block K partial
#pragma unroll
    for (int o = 32; o > 0; o >>= 1) km = max(km, __shfl_down(km, o));
    if (lane == 0) s_kp[w] = km;
    __syncthreads();
    if (t == 0) {
        int kk = 0;
#pragma unroll
        for (int k = 0; k < 16; ++k) kk = max(kk, s_kp[k]);
        kpart[blk] = (unsigned)kk;
        ovfp[blk] = (unsigned)s_ovf;
    }
}

__global__ void __launch_bounds__(1024) wl_mega_k(const int* __restrict__ src,
                                                  const int* __restrict__ dstp,
                                                  const int* __restrict__ lab0,
                                                  const float* __restrict__ hw,
                                                  const unsigned int* __restrict__ csr,
                                                  const unsigned int* __restrict__ degarr,
                                                  const unsigned int* __restrict__ kpart,
                                                  const unsigned int* __restrict__ ovfp,
                                                  unsigned int* __restrict__ feats,
                                                  float* __restrict__ diag) {
    __shared__ union {
        unsigned int chunk[N * WPR];                // fallback path: 128KB bitmask
        struct {
            unsigned short nbr[CSR_SLOTS];          // fallback path CSR
            struct {                                // Phase B: rank arrays 16KB
                int hist[N];
                int scan[N];
                float grp[N];
                int flag[N];
            } pb;
        } s;
    } u;
    __shared__ int s_lab[N + 2];                    // +sentinel slot (=0)
    __shared__ unsigned int s_feats[N];
    __shared__ int s_wsum[16];
    __shared__ int s_kp[16];
    __shared__ float s_mn[16], s_mx[16];
    __shared__ int s_anytie;
    int b = blockIdx.x, t = threadIdx.x;
    int lane = t & 63, w = t >> 6;

    int l0 = lab0[(size_t)b * N + t];
    float w0 = hw[0], w1 = hw[1];
    uint4 ov = *((const uint4*)(ovfp + (b << 2)));
    uint4 kq = *((const uint4*)(kpart + (b << 2)));
    int ovfg = (int)(ov.x | ov.y | ov.z | ov.w);    // block-uniform

    int vdeg, vpairs;
    float Kf;
    int lab_reg = l0;
    unsigned int pw[MAXP];
    const unsigned int* p_fb;                       // high-deg fallback source

    if (!ovfg) {
        // ---- Phase A-lite: CSR preloaded by csr_k ----
        vdeg = (int)degarr[(size_t)b * N + t];
        vpairs = (vdeg + 1) >> 1;
        Kf = (float)max(max(kq.x, kq.y), max(kq.z, kq.w));
        const unsigned int* crow = csr + (size_t)(b * N + t) * CSR_STRIDE;
        p_fb = crow;
#pragma unroll
        for (int k = 0; k < MAXP; ++k)
            pw[k] = (k < vpairs) ? crow[k] : SENT_PAIR;
        s_lab[t] = l0;
        s_feats[t] = 0;
        u.s.pb.hist[t] = 0;
        u.s.pb.flag[t] = 0;
        if (t == 0) { s_lab[N] = 0; s_anytie = 0; }
        __syncthreads();                                    // P0
#pragma unroll
        for (int v = 0; v < 16; ++v) {              // init label bincount
            unsigned long long m = __ballot(l0 == v);
            if (lane == v) {
                int c = __popcll(m);
                if (c) atomicAdd(&s_feats[v], (unsigned)c);
            }
        }
    } else {
        // ---- fallback: full in-kernel Phase A (R25-proven) ----
        const int* sg = src + (size_t)b * E;
        const int* dg_ = dstp + (size_t)b * E;
        int es[16], ed[16];
#pragma unroll
        for (int k = 0; k < 16; ++k) {
            es[k] = sg[t + k * 1024];
            ed[k] = dg_[t + k * 1024];
        }
#pragma unroll
        for (int k = 0; k < 8; ++k)
            ((uint4*)u.chunk)[t + k * 1024] = make_uint4(0, 0, 0, 0);
        s_lab[t] = l0;
        s_feats[t] = 0;
        if (t == 0) { s_lab[N] = 0; s_anytie = 0; }
        __syncthreads();                                    // P0
#pragma unroll
        for (int v = 0; v < 16; ++v) {
            unsigned long long m = __ballot(l0 == v);
            if (lane == v) {
                int c = __popcll(m);
                if (c) atomicAdd(&s_feats[v], (unsigned)c);
            }
        }
#pragma unroll
        for (int k = 0; k < 16; ++k) {
            int wlog = ed[k] >> 5;
            int g = wlog >> 2;
            int p = (g + es[k]) & 7;
            atomicOr(&u.chunk[es[k] * WPR + p * 4 + (wlog & 3)], 1u << (ed[k] & 31));
        }
        __syncthreads();                                    // C2
        uint4 r[8];
        {
            const uint4* row4 = (const uint4*)(u.chunk + t * WPR);
#pragma unroll
            for (int g = 0; g < 8; ++g)
                r[g] = row4[(g + t) & 7];
        }
        __syncthreads();                                    // C3
        int dg = 0;
#pragma unroll
        for (int k = 0; k < 8; ++k)
            dg += __popc(r[k].x) + __popc(r[k].y) + __popc(r[k].z) + __popc(r[k].w);
        int alloc = (dg + 1) & ~1;
        int f = alloc;
#pragma unroll
        for (int d2 = 1; d2 < 64; d2 <<= 1) {
            int v = __shfl_up(f, d2);
            if (lane >= d2) f += v;
        }
        int km = dg;
#pragma unroll
        for (int o = 32; o > 0; o >>= 1) km = max(km, __shfl_down(km, o));
        if (lane == 63) s_wsum[w] = f;
        if (lane == 0)  s_kp[w] = km;
        __syncthreads();                                    // A1
        int start;
        {
            int vv = ((lane & 15) < w) ? s_wsum[lane & 15] : 0;
#pragma unroll
            for (int m2 = 1; m2 < 16; m2 <<= 1) vv += __shfl_xor(vv, m2);
            start = (f - alloc) + vv;
            int kk = s_kp[lane & 15];
#pragma unroll
            for (int m2 = 8; m2 >= 1; m2 >>= 1) kk = max(kk, __shfl_xor(kk, m2));
            Kf = (float)kk;
        }
        u.s.pb.hist[t] = 0;
        u.s.pb.flag[t] = 0;
        {
            int idx = start;
#pragma unroll
            for (int k = 0; k < 8; ++k) {
                unsigned int wv[4] = { r[k].x, r[k].y, r[k].z, r[k].w };
#pragma unroll
                for (int c2 = 0; c2 < 4; ++c2) {
                    unsigned int word = wv[c2];
                    int bb = (k * 4 + c2) << 5;
                    while (word) {
                        int j = __ffs(word) - 1;
                        word &= word - 1;
                        u.s.nbr[idx++] = (unsigned short)(bb + j);
                    }
                }
            }
            if (dg & 1) u.s.nbr[idx] = (unsigned short)N;
        }
        __syncthreads();                                    // A3
        vdeg = dg;
        vpairs = alloc >> 1;
        p_fb = (const unsigned int*)u.s.nbr + (start >> 1);
#pragma unroll
        for (int k = 0; k < MAXP; ++k)
            pw[k] = (k < vpairs) ? p_fb[k] : SENT_PAIR;
    }

    // ---- Phase B: 5 WL iterations (R25-proven structure) ----
    int nfast = 0;                                  // fast-path feats counter
    for (int it = 0; it < NITER; ++it) {
        int ssum = 0;
#pragma unroll
        for (int k = 0; k < MAXP; ++k) {            // unconditional: 40 gathers
            unsigned int pr = pw[k];
            ssum += s_lab[pr & 0xFFFFu] + s_lab[pr >> 16];
        }
        for (int k = MAXP; k < vpairs; ++k) {       // rare high-deg fallback
            unsigned int pr = p_fb[k];
            ssum += s_lab[pr & 0xFFFFu] + s_lab[pr >> 16];
        }
        float t1 = __fmul_rn(__fmul_rn(Kf, w0), (float)lab_reg);
        float t2 = __fmul_rn(w1, __fsub_rn(__fadd_rn((float)ssum, (float)vdeg), Kf));
        float h  = __fadd_rn(t1, t2);

        float mn = h, mx = h;
#pragma unroll
        for (int o = 32; o > 0; o >>= 1) {
            mn = fminf(mn, __shfl_down(mn, o));
            mx = fmaxf(mx, __shfl_down(mx, o));
        }
        if (lane == 0) { s_mn[w] = mn; s_mx[w] = mx; }
        __syncthreads();                                    // B1
        float fmn, span;
        {
            float a = s_mn[lane & 15];
            float cmx = s_mx[lane & 15];
#pragma unroll
            for (int m2 = 8; m2 >= 1; m2 >>= 1) {
                a = fminf(a, __shfl_xor(a, m2));
                cmx = fmaxf(cmx, __shfl_xor(cmx, m2));
            }
            fmn = a;
            span = cmx - a;
        }
        float scale = (span > 0.f) ? (1023.0f / span) : 0.f;
        int bucket = min((int)((h - fmn) * scale), 1023);   // order-preserving
        int off_in = atomicAdd(&u.s.pb.hist[bucket], 1);
        __syncthreads();                                    // B3

        int f = u.s.pb.hist[t];
#pragma unroll
        for (int d2 = 1; d2 < 64; d2 <<= 1) {
            int v = __shfl_up(f, d2);
            if (lane >= d2) f += v;
        }
        if (lane == 63) s_wsum[w] = f;
        __syncthreads();                                    // B4
        {   // all-wave redundant exclusive wave base -> register
            int vv = ((lane & 15) < w) ? s_wsum[lane & 15] : 0;
#pragma unroll
            for (int m2 = 1; m2 < 16; m2 <<= 1) vv += __shfl_xor(vv, m2);
            u.s.pb.scan[t] = f + vv;
        }
        __syncthreads();                                    // B6

        int bs = u.s.pb.scan[bucket] - u.s.pb.hist[bucket];
        int be = u.s.pb.scan[bucket];
        u.s.pb.grp[bs + off_in] = h;
        __syncthreads();                                    // B7

        int cr = bs;                // lower buckets strictly less (monotone map)
        int eq = 0;
        for (int k = bs; k < be; ++k) {
            float g = u.s.pb.grp[k];
            cr += (g < h);
            eq += (g == h);
        }
        if (eq > 1) s_anytie = it + 1;  // sentinel: stale iters self-invalidate
        u.s.pb.hist[t] = 0;             // re-zero for next iter
        s_lab[t] = cr;                  // optimistic fast-path rank
        __syncthreads();                                    // B9
        if (s_anytie == it + 1) {       // rare: dense-rank repair pass
            u.s.pb.flag[cr] = 1;        // class start (same class -> same cr)
            __syncthreads();                                // T1
            int f2 = u.s.pb.flag[t];
#pragma unroll
            for (int d2 = 1; d2 < 64; d2 <<= 1) {
                int v = __shfl_up(f2, d2);
                if (lane >= d2) f2 += v;
            }
            if (lane == 63) s_wsum[w] = f2;
            __syncthreads();                                // T2
            {
                int vv = ((lane & 15) < w) ? s_wsum[lane & 15] : 0;
#pragma unroll
                for (int m2 = 1; m2 < 16; m2 <<= 1) vv += __shfl_xor(vv, m2);
                u.s.pb.scan[t] = f2 + vv;
            }
            u.s.pb.flag[t] = 0;         // own flag consumed above
            __syncthreads();                                // T4
            int rank = u.s.pb.scan[cr] - 1;
            s_lab[t] = rank;
            lab_reg = rank;
            atomicAdd(&s_feats[rank], 1u);
            __syncthreads();                                // T5: labels visible
        } else {
            lab_reg = cr;
            ++nfast;                    // permutation => every bin +1
        }
    }

    // ---- Phase C: feats out + fused diag[b] (int exact) ----
    unsigned int fv = s_feats[t] + (unsigned)nfast;
    feats[(size_t)b * N + t] = fv;
    int sq = (int)(fv * fv);
#pragma unroll
    for (int o = 32; o > 0; o >>= 1) sq += __shfl_down(sq, o);
    if (lane == 0) s_wsum[w] = sq;
    __syncthreads();
    if (t == 0) {
        int tot = 0;
#pragma unroll
        for (int k = 0; k < 16; ++k) tot += s_wsum[k];
        diag[b] = (float)tot;
    }
}

// gram+normalize fused: one block per row i; f_i staged in LDS; int dots
// exact. 1024 threads, 16 waves x 4 j's each (serial chain 4 iterations).
__global__ void __launch_bounds__(1024) gram_k(const unsigned int* __restrict__ feats,
                                               const float* __restrict__ diag,
                                               float* __restrict__ out) {
    __shared__ unsigned int s_fi[N];
    int i = blockIdx.x, t = threadIdx.x;
    int lane = t & 63, w = t >> 6;
    if (t < 256)
        ((uint4*)s_fi)[t] = ((const uint4*)(feats + (size_t)i * N))[t];
    __syncthreads();
    float di = diag[i];
#pragma unroll
    for (int jj = 0; jj < 4; ++jj) {
        int j = w * 4 + jj;
        const uint4* fj = (const uint4*)(feats + (size_t)j * N);
        const uint4* fi = (const uint4*)s_fi;
        int s = 0;
#pragma unroll
        for (int k = 0; k < 4; ++k) {
            uint4 vb = fj[lane + k * 64];
            uint4 va = fi[lane + k * 64];
            s += (int)(va.x * vb.x) + (int)(va.y * vb.y)
               + (int)(va.z * vb.z) + (int)(va.w * vb.w);
        }
#pragma unroll
        for (int off = 32; off > 0; off >>= 1) s += __shfl_down(s, off);
        if (lane == 0) out[i * B + j] = (float)s / sqrtf(di * diag[j]);
    }
}

extern "C" void kernel_launch(void* const* d_in, const int* in_sizes, int n_in,
                              void* d_out, int out_size, void* d_ws, size_t ws_size,
                              hipStream_t stream) {
    const int*   esrc = (const int*)d_in[0];
    const int*   edst = (const int*)d_in[1];
    const int*   lab0 = (const int*)d_in[2];
    const float* hw   = (const float*)d_in[3];

    char* ws = (char*)d_ws;
    unsigned int* feats = (unsigned int*)(ws + FEATS_OFF);
    float*        diag  = (float*)(ws + DIAG_OFF);
    unsigned int* csr   = (unsigned int*)(ws + CSR_OFF);
    unsigned int* degar = (unsigned int*)(ws + DEG_OFF);
    unsigned int* kpart = (unsigned int*)(ws + KPART_OFF);
    unsigned int* ovfp  = (unsigned int*)(ws + OVFP_OFF);

    csr_k<<<B * 4, 1024, 0, stream>>>(esrc, edst, csr, degar, kpart, ovfp);
    wl_mega_k<<<B, 1024, 0, stream>>>(esrc, edst, lab0, hw, csr, degar, kpart,
                                      ovfp, feats, diag);
    gram_k<<<B, 1024, 0, stream>>>(feats, diag, (float*)d_out);
}

// Round 7
// 98.281 us; speedup vs baseline: 1.1316x; 1.1316x over previous
//
#include <hip/hip_runtime.h>

#define B 64
#define N 1024
#define E 16384
#define WPR 32          // words per adjacency row = N/32
#define NITER 5
#define CSR_SLOTS (E + N)   // even-aligned per-node alloc: <=1 pad slot/node
#define MAXP 20             // pair-words cached in registers (deg<=40; LDS fallback beyond)
#define SENT_PAIR 0x04000400u   // (N<<16)|N : both halves index s_lab[N]==0
#define CAP 8               // grp2 slots per bucket (overflow -> slow path)
#define GSTRIDE 9           // grp2 row stride (9 coprime 32 => bank-conflict-free)

// ---- workspace layout (bytes) ---- (NO memset: feats/diag fully stored
// before any read; harness 0xAA poison harmless)
#define FEATS_OFF 0
#define DIAG_OFF  ((size_t)B * N * 4)

// R29: revert R28 (CSR-split regressed +11us: 4x redundant edge scan + 8MB
// global round-trip + 3rd launch). Two pure serial-chain cuts on the R25
// base: (a) A3 barrier DELETED — pack and pw-preload touch only the
// thread's OWN nbr bytes; same-wave DS ops are serviced in order, so a
// compiler fence suffices. (b) B7 removed via fixed-slot grp2 at STRIDE 9
// (R27 used stride 8 => bucket*8 mod 32 had 4 residues => 16-way bank
// conflict on every compare read, offsetting the 5 removed barriers; 9 is
// coprime with 32 => conflict-free). Fast path: 5 barriers/iter.
__global__ void __launch_bounds__(1024) wl_mega_k(const int* __restrict__ src,
                                                  const int* __restrict__ dstp,
                                                  const int* __restrict__ lab0,
                                                  const float* __restrict__ hw,
                                                  unsigned int* __restrict__ feats,
                                                  float* __restrict__ diag) {
    __shared__ union {
        unsigned int chunk[N * WPR];                // Phase A1: 128KB full bitmask
        struct {
            unsigned short nbr[CSR_SLOTS];          // Phase A2/B: 34816B CSR (self-read only)
            struct {                                // Phase B: rank arrays
                int hist[N];
                int scan[N];
                float grp[N];                       // slow-path ordered groups
                int flag[N];
                float grp2[N * GSTRIDE];            // fast-path groups, 36KB
            } pb;
        } s;
    } u;
    __shared__ int s_lab[N + 2];                    // +sentinel slot (=0)
    __shared__ unsigned int s_feats[N];
    __shared__ int s_wsum[16];
    __shared__ int s_kp[16];
    __shared__ float s_mn[16], s_mx[16];
    __shared__ int s_anytie;
    __shared__ int s_ovf;
    int b = blockIdx.x, t = threadIdx.x;
    int lane = t & 63, w = t >> 6;

    // ---- Phase A0: edge loads first (L3 latency overlaps LDS zero) ----
    const int* sg = src + (size_t)b * E;
    const int* dg_ = dstp + (size_t)b * E;
    int es[16], ed[16];
#pragma unroll
    for (int k = 0; k < 16; ++k) {                  // coalesced, 1 block/graph
        es[k] = sg[t + k * 1024];
        ed[k] = dg_[t + k * 1024];
    }
    int l0 = lab0[(size_t)b * N + t];
    float w0 = hw[0], w1 = hw[1];
    // zero 128KB bitmask while loads are in flight
#pragma unroll
    for (int k = 0; k < 8; ++k)
        ((uint4*)u.chunk)[t + k * 1024] = make_uint4(0, 0, 0, 0);
    s_lab[t] = l0;
    s_feats[t] = 0;
    if (t == 0) { s_lab[N] = 0; s_anytie = 0; s_ovf = 0; }
    __syncthreads();                                        // P0
    // init label bincount (labels < 16) via ballot
#pragma unroll
    for (int v = 0; v < 16; ++v) {
        unsigned long long m = __ballot(l0 == v);
        if (lane == v) {
            int c = __popcll(m);
            if (c) atomicAdd(&s_feats[v], (unsigned)c);
        }
    }

    // ---- Phase A1: bitmask scatter (swizzled), row -> r[8] ----
#pragma unroll
    for (int k = 0; k < 16; ++k) {
        int wlog = ed[k] >> 5;                      // logical word 0..31
        int g = wlog >> 2;                          // logical group 0..7
        int p = (g + es[k]) & 7;                    // swizzled slot
        atomicOr(&u.chunk[es[k] * WPR + p * 4 + (wlog & 3)], 1u << (ed[k] & 31));
    }
    __syncthreads();                                        // C2
    uint4 r[8];
    {
        const uint4* row4 = (const uint4*)(u.chunk + t * WPR);
#pragma unroll
        for (int g = 0; g < 8; ++g)
            r[g] = row4[(g + t) & 7];               // conflict-free (swizzled)
    }
    __syncthreads();                                        // C3: chunk reusable

    // ---- Phase A2: deg/alloc/K/CSR starts + pack ----
    int dg = 0;
#pragma unroll
    for (int k = 0; k < 8; ++k)
        dg += __popc(r[k].x) + __popc(r[k].y) + __popc(r[k].z) + __popc(r[k].w);
    int alloc = (dg + 1) & ~1;                      // even per-node CSR alloc

    int f = alloc;                                  // wave scan of alloc
#pragma unroll
    for (int d2 = 1; d2 < 64; d2 <<= 1) {
        int v = __shfl_up(f, d2);
        if (lane >= d2) f += v;
    }
    int km = dg;
#pragma unroll
    for (int o = 32; o > 0; o >>= 1) km = max(km, __shfl_down(km, o));
    if (lane == 63) s_wsum[w] = f;
    if (lane == 0)  s_kp[w] = km;
    __syncthreads();                                        // A1
    // all-wave redundant combine: wave-exclusive base + block K, in registers
    float Kf;
    int start;
    {
        int vv = ((lane & 15) < w) ? s_wsum[lane & 15] : 0;
#pragma unroll
        for (int m2 = 1; m2 < 16; m2 <<= 1) vv += __shfl_xor(vv, m2);
        start = (f - alloc) + vv;                   // even => u32-aligned
        int kk = s_kp[lane & 15];
#pragma unroll
        for (int m2 = 8; m2 >= 1; m2 >>= 1) kk = max(kk, __shfl_xor(kk, m2));
        Kf = (float)kk;
    }
    u.s.pb.hist[t] = 0;                             // aliases chunk: re-init
    u.s.pb.flag[t] = 0;

    // pack own row's set bits ONCE -> u16 list; pad odd deg with sentinel N
    {
        int idx = start;
#pragma unroll
        for (int k = 0; k < 8; ++k) {
            unsigned int wv[4] = { r[k].x, r[k].y, r[k].z, r[k].w };
#pragma unroll
            for (int c2 = 0; c2 < 4; ++c2) {
                unsigned int word = wv[c2];
                int bb = (k * 4 + c2) << 5;
                while (word) {
                    int j = __ffs(word) - 1;
                    word &= word - 1;
                    u.s.nbr[idx++] = (unsigned short)(bb + j);
                }
            }
        }
        if (dg & 1) u.s.nbr[idx] = (unsigned short)N;   // sentinel -> adds 0
    }
    // NO barrier: pw preload reads only this thread's own nbr bytes (same-
    // wave DS ops are serviced in order); fence stops compiler reordering.
    asm volatile("" ::: "memory");

    int vdeg = dg;
    int vpstart = start >> 1;
    int vpairs = alloc >> 1;
    int lab_reg = l0;
    const unsigned int* nbr32 = (const unsigned int*)u.s.nbr;
    // iteration-invariant pair-words -> registers; sentinel-pad to MAXP so
    // the hot loop needs NO predication (sentinel reads broadcast s_lab[N]=0)
    unsigned int pw[MAXP];
#pragma unroll
    for (int k = 0; k < MAXP; ++k)
        pw[k] = (k < vpairs) ? nbr32[vpstart + k] : SENT_PAIR;

    // ---- Phase B: 5 WL iterations ----
    int nfast = 0;                                  // fast-path feats counter
    for (int it = 0; it < NITER; ++it) {
        int ssum = 0;
#pragma unroll
        for (int k = 0; k < MAXP; ++k) {            // unconditional: 40 gathers
            unsigned int pr = pw[k];
            ssum += s_lab[pr & 0xFFFFu] + s_lab[pr >> 16];
        }
        for (int k = MAXP; k < vpairs; ++k) {       // rare high-deg fallback
            unsigned int pr = nbr32[vpstart + k];
            ssum += s_lab[pr & 0xFFFFu] + s_lab[pr >> 16];
        }
        float t1 = __fmul_rn(__fmul_rn(Kf, w0), (float)lab_reg);
        float t2 = __fmul_rn(w1, __fsub_rn(__fadd_rn((float)ssum, (float)vdeg), Kf));
        float h  = __fadd_rn(t1, t2);

        float mn = h, mx = h;
#pragma unroll
        for (int o = 32; o > 0; o >>= 1) {
            mn = fminf(mn, __shfl_down(mn, o));
            mx = fmaxf(mx, __shfl_down(mx, o));
        }
        if (lane == 0) { s_mn[w] = mn; s_mx[w] = mx; }
        __syncthreads();                                    // B1
        // all-wave redundant min/max combine -> registers (no 2nd barrier)
        float fmn, span;
        {
            float a = s_mn[lane & 15];
            float cmx = s_mx[lane & 15];
#pragma unroll
            for (int m2 = 8; m2 >= 1; m2 >>= 1) {
                a = fminf(a, __shfl_xor(a, m2));
                cmx = fmaxf(cmx, __shfl_xor(cmx, m2));
            }
            fmn = a;
            span = cmx - a;
        }
        float scale = (span > 0.f) ? (1023.0f / span) : 0.f;
        int bucket = min((int)((h - fmn) * scale), 1023);   // order-preserving
        int off_in = atomicAdd(&u.s.pb.hist[bucket], 1);
        if (off_in < CAP) u.s.pb.grp2[bucket * GSTRIDE + off_in] = h; // B3 covers
        else s_ovf = 1;                                               // rare
        __syncthreads();                                    // B3

        int ovf = s_ovf;                            // uniform post-B3
        int cnt = u.s.pb.hist[bucket];              // final bucket count (reg)
        int c_in = 0, eq = 0;
        if (!ovf) {                                 // conflict-free (stride 9)
            for (int j = 0; j < cnt; ++j) {
                float g = u.s.pb.grp2[bucket * GSTRIDE + j];
                c_in += (g < h);
                eq += (g == h);
            }
        }
        f = u.s.pb.hist[t];
#pragma unroll
        for (int d2 = 1; d2 < 64; d2 <<= 1) {
            int v = __shfl_up(f, d2);
            if (lane >= d2) f += v;
        }
        if (lane == 63) s_wsum[w] = f;
        __syncthreads();                                    // B4
        {   // all-wave redundant exclusive wave base -> register
            int vv = ((lane & 15) < w) ? s_wsum[lane & 15] : 0;
#pragma unroll
            for (int m2 = 1; m2 < 16; m2 <<= 1) vv += __shfl_xor(vv, m2);
            u.s.pb.scan[t] = f + vv;
        }
        u.s.pb.hist[t] = 0;             // readers latched cnt pre-B4
        if (t == 0) s_ovf = 0;          // readers latched ovf pre-B4
        __syncthreads();                                    // B6

        int cr;
        if (!ovf) {
            cr = (u.s.pb.scan[bucket] - cnt) + c_in;    // dense rank iff no ties
        } else {                        // slow path: scan-ordered groups
            int bs = u.s.pb.scan[bucket] - cnt;
            u.s.pb.grp[bs + off_in] = h;
            __syncthreads();                                // B7 (rare)
            cr = bs;
            eq = 0;
            for (int k = bs; k < bs + cnt; ++k) {
                float g = u.s.pb.grp[k];
                cr += (g < h);
                eq += (g == h);
            }
        }
        if (eq > 1) s_anytie = it + 1;  // sentinel: stale iters self-invalidate
        s_lab[t] = cr;                  // optimistic fast-path rank
        __syncthreads();                                    // B9
        if (s_anytie == it + 1) {       // rare: dense-rank repair pass
            u.s.pb.flag[cr] = 1;        // class start (same class -> same cr)
            __syncthreads();                                // T1
            int f2 = u.s.pb.flag[t];
#pragma unroll
            for (int d2 = 1; d2 < 64; d2 <<= 1) {
                int v = __shfl_up(f2, d2);
                if (lane >= d2) f2 += v;
            }
            if (lane == 63) s_wsum[w] = f2;
            __syncthreads();                                // T2
            {   // all-wave redundant exclusive wave base -> register
                int vv = ((lane & 15) < w) ? s_wsum[lane & 15] : 0;
#pragma unroll
                for (int m2 = 1; m2 < 16; m2 <<= 1) vv += __shfl_xor(vv, m2);
                u.s.pb.scan[t] = f2 + vv;
            }
            u.s.pb.flag[t] = 0;         // own flag consumed above
            __syncthreads();                                // T4
            int rank = u.s.pb.scan[cr] - 1;
            s_lab[t] = rank;
            lab_reg = rank;
            atomicAdd(&s_feats[rank], 1u);
            __syncthreads();                                // T5: labels visible
        } else {
            lab_reg = cr;
            ++nfast;                    // permutation => every bin +1
        }
    }

    // ---- Phase C: feats out + fused diag[b] (int exact) ----
    unsigned int fv = s_feats[t] + (unsigned)nfast;
    feats[(size_t)b * N + t] = fv;
    int sq = (int)(fv * fv);
#pragma unroll
    for (int o = 32; o > 0; o >>= 1) sq += __shfl_down(sq, o);
    if (lane == 0) s_wsum[w] = sq;
    __syncthreads();
    if (t == 0) {
        int tot = 0;
#pragma unroll
        for (int k = 0; k < 16; ++k) tot += s_wsum[k];
        diag[b] = (float)tot;
    }
}

// gram+normalize fused: one block per row i; f_i staged in LDS; int dots
// exact. 1024 threads, 16 waves x 4 j's each (serial chain 4 iterations).
__global__ void __launch_bounds__(1024) gram_k(const unsigned int* __restrict__ feats,
                                               const float* __restrict__ diag,
                                               float* __restrict__ out) {
    __shared__ unsigned int s_fi[N];
    int i = blockIdx.x, t = threadIdx.x;
    int lane = t & 63, w = t >> 6;
    if (t < 256)
        ((uint4*)s_fi)[t] = ((const uint4*)(feats + (size_t)i * N))[t];
    __syncthreads();
    float di = diag[i];
#pragma unroll
    for (int jj = 0; jj < 4; ++jj) {
        int j = w * 4 + jj;
        const uint4* fj = (const uint4*)(feats + (size_t)j * N);
        const uint4* fi = (const uint4*)s_fi;
        int s = 0;
#pragma unroll
        for (int k = 0; k < 4; ++k) {
            uint4 vb = fj[lane + k * 64];
            uint4 va = fi[lane + k * 64];
            s += (int)(va.x * vb.x) + (int)(va.y * vb.y)
               + (int)(va.z * vb.z) + (int)(va.w * vb.w);
        }
#pragma unroll
        for (int off = 32; off > 0; off >>= 1) s += __shfl_down(s, off);
        if (lane == 0) out[i * B + j] = (float)s / sqrtf(di * diag[j]);
    }
}

extern "C" void kernel_launch(void* const* d_in, const int* in_sizes, int n_in,
                              void* d_out, int out_size, void* d_ws, size_t ws_size,
                              hipStream_t stream) {
    const int*   esrc = (const int*)d_in[0];
    const int*   edst = (const int*)d_in[1];
    const int*   lab0 = (const int*)d_in[2];
    const float* hw   = (const float*)d_in[3];

    char* ws = (char*)d_ws;
    unsigned int* feats = (unsigned int*)(ws + FEATS_OFF);
    float*        diag  = (float*)(ws + DIAG_OFF);

    wl_mega_k<<<B, 1024, 0, stream>>>(esrc, edst, lab0, hw, feats, diag);
    gram_k<<<B, 1024, 0, stream>>>(feats, diag, (float*)d_out);
}